// Round 18
// baseline (739.857 us; speedup 1.0000x reference)
//
#include <hip/hip_runtime.h>

// dims
#define BB 2
#define TT 2048
#define HID 2048
#define HK 16
#define HV 32
#define DK 128
#define DV 128
#define KW 4
#define KEY_DIM 2048
#define VAL_DIM 4096
#define CONV_DIM 8192
#define N1PAD 12544     // 12352 padded to 256
#define M_ROWS 4096     // B*T
#define CC 64           // scan chunk length

typedef __attribute__((ext_vector_type(8))) short short8;
typedef __attribute__((ext_vector_type(8))) unsigned short ushort8;
typedef __attribute__((ext_vector_type(4))) float f32x4;

__device__ __forceinline__ unsigned short f2bf(float f) {
  union { float f; unsigned int u; } v; v.f = f;
  unsigned int r = v.u + 0x7FFFu + ((v.u >> 16) & 1u);
  return (unsigned short)(r >> 16);
}
__device__ __forceinline__ float bf2f(unsigned short u) {
  union { unsigned int u; float f; } v; v.u = ((unsigned int)u) << 16; return v.f;
}

// pure-VALU cross-lane ops via DPP
template <int CTRL>
__device__ __forceinline__ float dpp_add(float v) {
  union { float f; int i; } a, b;
  a.f = v;
  b.i = __builtin_amdgcn_update_dpp(0, a.i, CTRL, 0xf, 0xf, true);
  return a.f + b.f;
}
template <int CTRL>
__device__ __forceinline__ int dpp_mov(int v) {
  return __builtin_amdgcn_update_dpp(0, v, CTRL, 0xf, 0xf, true);
}
__device__ __forceinline__ float row16_sum(float v) {
  v = dpp_add<0xB1>(v); v = dpp_add<0x4E>(v);
  v = dpp_add<0x141>(v); v = dpp_add<0x140>(v);
  return v;
}
__device__ __forceinline__ float row8_sum(float v) {
  v = dpp_add<0xB1>(v); v = dpp_add<0x4E>(v); v = dpp_add<0x141>(v);
  return v;
}

__device__ __forceinline__ void gload_lds16(const unsigned short* g, unsigned short* l) {
  __builtin_amdgcn_global_load_lds((const __attribute__((address_space(1))) unsigned int*)g,
                                   (__attribute__((address_space(3))) unsigned int*)l,
                                   16, 0, 0);
}
__device__ __forceinline__ void gload_lds4(const float* g, unsigned short* l) {
  __builtin_amdgcn_global_load_lds((const __attribute__((address_space(1))) unsigned int*)g,
                                   (__attribute__((address_space(3))) unsigned int*)l,
                                   4, 0, 0);
}

// swizzled LDS bf16 reads: rows of 256B (sh=8) / 128B (sh=7); byte ^= ((row&7)<<4)
__device__ __forceinline__ short8 ldswz8(const char* base, int row, int e16) {
  int L = (row << 8) + (e16 << 1);
  return *(const short8*)(base + (L ^ ((row & 7) << 4)));
}
__device__ __forceinline__ short8 ldswz7(const char* base, int row, int e16) {
  int L = (row << 7) + (e16 << 1);
  return *(const short8*)(base + (L ^ ((row & 7) << 4)));
}
// rows of 64B (BK=32): byte ^= ((row&3)<<4)
__device__ __forceinline__ short8 ldswz6(const char* base, int row, int e16) {
  int L = (row << 6) + (e16 << 1);
  return *(const short8*)(base + (L ^ ((row & 3) << 4)));
}

// ---------------- conversions ----------------
__global__ void cvt_bf16(const float* __restrict__ in, unsigned short* __restrict__ out) {
  long i = ((long)blockIdx.x * 256 + threadIdx.x) * 4;
  float4 v = *(const float4*)&in[i];
  unsigned long long p = (unsigned long long)f2bf(v.x)
                       | ((unsigned long long)f2bf(v.y) << 16)
                       | ((unsigned long long)f2bf(v.z) << 32)
                       | ((unsigned long long)f2bf(v.w) << 48);
  *(unsigned long long*)&out[i] = p;
}

__global__ void build_wcat(const float* __restrict__ wqkv, const float* __restrict__ wz,
                           const float* __restrict__ wb, const float* __restrict__ wa,
                           unsigned short* __restrict__ wcat) {
  long idx = (long)blockIdx.x * 256 + threadIdx.x;
  long e = idx * 4;
  long r = e >> 11;
  int cc = (int)(e & 2047);
  unsigned long long p = 0ULL;
  if (r < 12352) {
    const float* src;
    if (r < 8192)       src = wqkv + r * 2048;
    else if (r < 12288) src = wz + (r - 8192) * 2048;
    else if (r < 12320) src = wb + (r - 12288) * 2048;
    else                src = wa + (r - 12320) * 2048;
    float4 v = *(const float4*)&src[cc];
    p = (unsigned long long)f2bf(v.x)
      | ((unsigned long long)f2bf(v.y) << 16)
      | ((unsigned long long)f2bf(v.z) << 32)
      | ((unsigned long long)f2bf(v.w) << 48);
  }
  *(unsigned long long*)&wcat[e] = p;
}

// ---------------- staging helpers ----------------
// rows of 64 bf16 = 128B, swz7 (2-phase gemm2)
__device__ __forceinline__ void stage256(const unsigned short* __restrict__ G, long rb, int K,
                                         int kt, char* region, int r, int tid, int wid) {
  int i = r * 512 + tid;
  int row = i >> 3;
  int D = i << 4;
  int eb = (D ^ ((row & 7) << 4)) & 127;
  const unsigned short* src = G + (rb + row) * (long)K + kt * 64 + (eb >> 1);
  gload_lds16(src, (unsigned short*)region + r * 4096 + wid * 512);
}
// rows of 32 bf16 = 64B, swz6 (pipelined gemm1); 256 rows x 64B = 16KB per call-pair
__device__ __forceinline__ void stage32(const unsigned short* __restrict__ G, long rb, int K,
                                        int kt, char* region, int r, int tid, int wid) {
  int i = r * 512 + tid;                 // chunk 0..1023, dest byte = i*16
  int row = i >> 2;                      // 0..255
  int eb = ((i & 3) << 4) ^ ((row & 3) << 4);
  const unsigned short* src = G + (rb + row) * (long)K + kt * 32 + (eb >> 1);
  gload_lds16(src, (unsigned short*)region + r * 4096 + wid * 512);
}

// ---------------- GEMM1 256x256, BK=32, 4-buffer counted-vmcnt pipeline ----------------
__global__ __launch_bounds__(512, 2) void gemm256(const unsigned short* __restrict__ A,
                                                  const unsigned short* __restrict__ Bw,
                                                  unsigned short* __restrict__ Cout,
                                                  int N, int K) {
  extern __shared__ char gs[];   // 4 x (A 16KB + B 16KB) = 131072
  const int tid = threadIdx.x, wid = tid >> 6, lane = tid & 63;
  const int lr = lane & 15, lq = lane >> 4;
  const long m0 = (long)blockIdx.y << 8;
  const long n0 = (long)blockIdx.x << 8;
  const int wr = wid >> 2, wc = wid & 3;        // wave tile 128x64
  const int nkt = K >> 5;                        // 64

  f32x4 acc[8][4] = {};

  // prologue: stage tiles 0,1,2 (12 VMEM instr/wave); wait oldest 4 (tile 0)
#pragma unroll
  for (int t = 0; t < 3; ++t) {
    char* nb = gs + t * 32768;
#pragma unroll
    for (int r = 0; r < 2; ++r) {
      stage32(A, m0, K, t, nb, r, tid, wid);
      stage32(Bw, n0, K, t, nb + 16384, r, tid, wid);
    }
  }
  asm volatile("s_waitcnt vmcnt(8)" ::: "memory");
  __builtin_amdgcn_s_barrier();

  for (int kt = 0; kt < nkt; ++kt) {
    const char* cur = gs + (kt & 3) * 32768;
    const char* cA = cur;
    const char* cB = cur + 16384;
    // issue tile kt+3 into buf[(kt+3)&3] (reads of it finished before last barrier)
    if (kt + 3 < nkt) {
      char* nb = gs + ((kt + 3) & 3) * 32768;
#pragma unroll
      for (int r = 0; r < 2; ++r) {
        stage32(A, m0, K, kt + 3, nb, r, tid, wid);
        stage32(Bw, n0, K, kt + 3, nb + 16384, r, tid, wid);
      }
    }
    short8 bf[4], af[8];
#pragma unroll
    for (int cf = 0; cf < 4; ++cf)
      bf[cf] = ldswz6(cB, wc * 64 + cf * 16 + lr, lq * 8);
#pragma unroll
    for (int rf = 0; rf < 8; ++rf)
      af[rf] = ldswz6(cA, wr * 128 + rf * 16 + lr, lq * 8);
    __builtin_amdgcn_s_setprio(1);
#pragma unroll
    for (int rf = 0; rf < 8; ++rf)
#pragma unroll
      for (int cf = 0; cf < 4; ++cf)
        acc[rf][cf] = __builtin_amdgcn_mfma_f32_16x16x32_bf16(af[rf], bf[cf], acc[rf][cf], 0, 0, 0);
    __builtin_amdgcn_s_setprio(0);
    // counted wait: ensure stage(kt+1) landed; keep later stages in flight
    if (kt + 3 < nkt)      asm volatile("s_waitcnt vmcnt(8)" ::: "memory");
    else if (kt + 2 < nkt) asm volatile("s_waitcnt vmcnt(4)" ::: "memory");
    else if (kt + 1 < nkt) asm volatile("s_waitcnt vmcnt(0)" ::: "memory");
    __builtin_amdgcn_s_barrier();
  }

  const long rbase = m0 + wr * 128 + lq * 4;
  const long cbase = n0 + wc * 64 + lr;
#pragma unroll
  for (int rf = 0; rf < 8; ++rf)
#pragma unroll
    for (int cf = 0; cf < 4; ++cf)
#pragma unroll
      for (int j = 0; j < 4; ++j)
        Cout[(rbase + rf * 16 + j) * N + cbase + cf * 16] = f2bf(acc[rf][cf][j]);
}

// ---------------- GEMM 128x256 tile, BK=64, 8 waves, dbuf, swizzled, f32 out (gemm2) ----------------
__global__ __launch_bounds__(512, 2) void gemm128x256(const unsigned short* __restrict__ A,
                                                      const unsigned short* __restrict__ Bw,
                                                      float* __restrict__ Cout,
                                                      int N, int K) {
  extern __shared__ char gs[];   // 2 x (A 16KB + B 32KB) = 98304
  const int tid = threadIdx.x, wid = tid >> 6, lane = tid & 63;
  const int lr = lane & 15, lq = lane >> 4;
  const long m0 = (long)blockIdx.y << 7;
  const long n0 = (long)blockIdx.x << 8;
  const int wr = wid >> 2, wc = wid & 3;   // wave tile 64x64
  const int nkt = K >> 6;

  f32x4 acc[4][4] = {};

#pragma unroll
  for (int r = 0; r < 2; ++r) stage256(A, m0, K, 0, gs, r, tid, wid);
#pragma unroll
  for (int r = 0; r < 4; ++r) stage256(Bw, n0, K, 0, gs + 16384, r, tid, wid);
  asm volatile("s_waitcnt vmcnt(0)" ::: "memory");
  __syncthreads();

  for (int kt = 0; kt < nkt; ++kt) {
    char* cur = gs + (kt & 1) * 49152;
    char* nxt = gs + ((kt + 1) & 1) * 49152;
    const char* cA = cur;
    const char* cB = cur + 16384;
    const bool pf = (kt + 1 < nkt);
    short8 bf[2][4];
#pragma unroll
    for (int p = 0; p < 4; ++p) {
      if (pf) {
        if (p < 2) stage256(A, m0, K, kt + 1, nxt, p, tid, wid);
        stage256(Bw, n0, K, kt + 1, nxt + 16384, p, tid, wid);
      }
      if (p == 0) {
#pragma unroll
        for (int ks = 0; ks < 2; ++ks)
#pragma unroll
          for (int cf = 0; cf < 4; ++cf)
            bf[ks][cf] = ldswz7(cB, wc * 64 + cf * 16 + lr, ks * 32 + lq * 8);
      }
      short8 af[2];
#pragma unroll
      for (int ks = 0; ks < 2; ++ks)
        af[ks] = ldswz7(cA, wr * 64 + p * 16 + lr, ks * 32 + lq * 8);
      __builtin_amdgcn_s_setprio(1);
#pragma unroll
      for (int ks = 0; ks < 2; ++ks)
#pragma unroll
        for (int cf = 0; cf < 4; ++cf)
          acc[p][cf] = __builtin_amdgcn_mfma_f32_16x16x32_bf16(
              af[ks], bf[ks][cf], acc[p][cf], 0, 0, 0);
      __builtin_amdgcn_s_setprio(0);
    }
    asm volatile("s_waitcnt vmcnt(0)" ::: "memory");
    __syncthreads();
  }

  const long rbase = m0 + wr * 64 + lq * 4;
  const long cbase = n0 + wc * 64 + lr;
#pragma unroll
  for (int rf = 0; rf < 4; ++rf)
#pragma unroll
    for (int cf = 0; cf < 4; ++cf)
#pragma unroll
      for (int j = 0; j < 4; ++j)
        Cout[(rbase + rf * 16 + j) * N + cbase + cf * 16] = acc[rf][cf][j];
}

// ---------------- depthwise causal conv1d + silu (+ fused l2norm for q,k) ----------------
__global__ __launch_bounds__(256) void conv_silu(const unsigned short* __restrict__ C1,
                                                 const float* __restrict__ convw,
                                                 unsigned short* __restrict__ qb,
                                                 unsigned short* __restrict__ kb,
                                                 unsigned short* __restrict__ vb) {
  const int bid = blockIdx.x;             // 512 = cb(4) * tblk(64) * b(2)
  const int cb = bid & 3, tblk = (bid >> 2) & 63, b = bid >> 8;
  const int c0 = cb * 2048 + threadIdx.x * 8;
  float w0[8], w1[8], w2[8], w3[8];
#pragma unroll
  for (int j = 0; j < 8; ++j) {
    float4 wv = *(const float4*)&convw[(c0 + j) * 4];
    w0[j] = wv.x; w1[j] = wv.y; w2[j] = wv.z; w3[j] = wv.w;
  }
  const int t0 = tblk * 32;
  const long rowbase = ((long)b * TT) * N1PAD + c0;
  float x0[8], x1[8], x2[8];
#pragma unroll
  for (int j = 0; j < 8; ++j) { x0[j] = 0.f; x1[j] = 0.f; x2[j] = 0.f; }
  if (t0 >= 1) { ushort8 r = *(const ushort8*)&C1[rowbase + (long)(t0 - 1) * N1PAD];
#pragma unroll
    for (int j = 0; j < 8; ++j) x2[j] = bf2f(r[j]); }
  if (t0 >= 2) { ushort8 r = *(const ushort8*)&C1[rowbase + (long)(t0 - 2) * N1PAD];
#pragma unroll
    for (int j = 0; j < 8; ++j) x1[j] = bf2f(r[j]); }
  if (t0 >= 3) { ushort8 r = *(const ushort8*)&C1[rowbase + (long)(t0 - 3) * N1PAD];
#pragma unroll
    for (int j = 0; j < 8; ++j) x0[j] = bf2f(r[j]); }

  const float nsc = (cb == 0) ? 0.08838834764831845f : 1.0f;
  for (int t = t0; t < t0 + 32; ++t) {
    ushort8 rr = *(const ushort8*)&C1[rowbase + (long)t * N1PAD];
    float ys[8];
#pragma unroll
    for (int j = 0; j < 8; ++j) {
      float x3 = bf2f(rr[j]);
      float y = w0[j] * x0[j] + w1[j] * x1[j] + w2[j] * x2[j] + w3[j] * x3;
      ys[j] = y / (1.f + __expf(-y));
      x0[j] = x1[j]; x1[j] = x2[j]; x2[j] = x3;
    }
    if (cb < 2) {
      float ss = 0.f;
#pragma unroll
      for (int j = 0; j < 8; ++j) ss = fmaf(ys[j], ys[j], ss);
      ss = row16_sum(ss);
      float sc = nsc / fmaxf(sqrtf(ss), 1e-12f);
#pragma unroll
      for (int j = 0; j < 8; ++j) ys[j] *= sc;
    }
    ushort8 outp;
#pragma unroll
    for (int j = 0; j < 8; ++j) outp[j] = f2bf(ys[j]);
    long m = (long)b * TT + t;
    if (cb == 0)      *(ushort8*)&qb[m * 2048 + threadIdx.x * 8] = outp;
    else if (cb == 1) *(ushort8*)&kb[m * 2048 + threadIdx.x * 8] = outp;
    else              *(ushort8*)&vb[m * 4096 + (cb - 2) * 2048 + threadIdx.x * 8] = outp;
  }
}

// ---------------- raw g (log decay) and beta ----------------
__global__ void gbeta(const unsigned short* __restrict__ C1, const float* __restrict__ Alog,
                      const float* __restrict__ dtb, float* __restrict__ graw, float* __restrict__ betab) {
  int idx = blockIdx.x * 256 + threadIdx.x;
  int m = idx >> 5, h = idx & 31;
  float a = bf2f(C1[(long)m * N1PAD + 12320 + h]);
  float bl = bf2f(C1[(long)m * N1PAD + 12288 + h]);
  float xsp = a + dtb[h];
  float sp = (xsp > 20.f) ? xsp : log1pf(expf(xsp));
  graw[idx] = -expf(Alog[h]) * sp;
  betab[idx] = 1.f / (1.f + expf(-bl));
}

// ---------------- chunked gated delta rule scan (MFMA WY-form, 512 thr coop, 97KB LDS) ----------------
// LDS map (bytes):
#define OFF_K   0          // [64][128] bf16 swz8 — 16384 (single buffer)
#define OFF_V   16384      // [64][32] bf16 linear — 4096
#define OFF_G   20480      // [64] f32
#define OFF_B2  20736      // [64] f32
#define OFF_KT  20992      // [128 dk][64 t] bf16, swz keyed dk&7 — 16384
#define OFF_SH  37376      // St hi [32][128] bf16 swz8 — 8192
#define OFF_SL  45568      // St lo — 8192
#define OFF_A2  53760      // [64][68] f32 padded — 17408
#define OFF_MM  71168      // M [64][64] bf16 swz7 — 8192
#define OFF_BT  79360      // Bt [32][64] bf16 swz7 — 4096
#define OFF_BT2 83456      // 4096
#define OFF_X   87552      // [64][33] f32 padded — 8448
#define OFF_CS  96000
#define OFF_EXC 96256
#define OFF_ECT 96512
#define SMEM_SZ 96768

__global__ __launch_bounds__(512, 2) void chunk_scan(const unsigned short* __restrict__ qb,
                                                     const unsigned short* __restrict__ kb,
                                                     const unsigned short* __restrict__ vb,
                                                     const float* __restrict__ graw,
                                                     const float* __restrict__ betab,
                                                     unsigned short* __restrict__ ob) {
  extern __shared__ char smem[];
  const int w = blockIdx.x;
  const int rdec = w >> 5, gdec = w & 31;
  const int bat = gdec >> 4, hk = gdec & 15;
  const int h = hk * 2 + (rdec >> 2), vc = rdec & 3;
  const int tid = threadIdx.x, wid = tid >> 6, lane = tid & 63;
  const int lr = lane & 15, lq = lane >> 4;
  const int rg = wid & 3, half = wid >> 2;
  const int mr = wid & 1, nc2 = (wid >> 1) & 3;

  const long kqoff = ((long)bat * TT) * 2048 + hk * 128;
  const long voff  = ((long)bat * TT) * 4096 + h * 128 + vc * 32;
  const long goff  = ((long)bat * TT) * 32 + h;

  f32x4 Smast[2] = {};

  auto stage_full = [&](int t0c) {
#pragma unroll
    for (int it = 0; it < 2; ++it) {
      int i = it * 512 + tid;
      int row = i >> 4;
      int L = ((i & 15) << 4) ^ ((row & 7) << 4);
      long grow = (long)(t0c + row) * 2048 + (L >> 1);
      gload_lds16(kb + kqoff + grow, (unsigned short*)(smem + OFF_K) + it * 4096 + wid * 512);
    }
    if (tid < 256)
      gload_lds16(vb + voff + (long)(t0c + (tid >> 2)) * 4096 + (tid & 3) * 8,
                  (unsigned short*)(smem + OFF_V) + wid * 512);
    if (wid == 6) gload_lds4(graw  + goff + (long)(t0c + lane) * 32, (unsigned short*)(smem + OFF_G));
    if (wid == 7) gload_lds4(betab + goff + (long)(t0c + lane) * 32, (unsigned short*)(smem + OFF_B2));
  };
  auto stage_part = [&](int t0c) {   // waves 4-7
    int tid2 = tid - 256, wid2 = wid - 4;
#pragma unroll
    for (int it = 0; it < 4; ++it) {
      int i = it * 256 + tid2;
      int row = i >> 4;
      int L = ((i & 15) << 4) ^ ((row & 7) << 4);
      long grow = (long)(t0c + row) * 2048 + (L >> 1);
      gload_lds16(kb + kqoff + grow, (unsigned short*)(smem + OFF_K) + it * 2048 + wid2 * 512);
    }
    gload_lds16(vb + voff + (long)(t0c + (tid2 >> 2)) * 4096 + (tid2 & 3) * 8,
                (unsigned short*)(smem + OFF_V) + wid2 * 512);
    if (wid == 4) gload_lds4(graw  + goff + (long)(t0c + lane) * 32, (unsigned short*)(smem + OFF_G));
    if (wid == 5) gload_lds4(betab + goff + (long)(t0c + lane) * 32, (unsigned short*)(smem + OFF_B2));
  };
  auto loadQ = [&](short8 (&qr)[4], int t0c) {
#pragma unroll
    for (int kk = 0; kk < 4; ++kk)
      qr[kk] = *(const short8*)&qb[kqoff + (long)(t0c + 16 * rg + lr) * 2048 + kk * 32 + lq * 8];
  };

  auto body = [&](int ct, short8 (&qcur)[4], short8 (&qnext)[4]) {
    // ---- T1: kT transpose (all 512); wave0 cumsum+exp tables ----
    {
      int tp = tid & 31, dkb = tid >> 5;
      short8 r0 = ldswz8(smem + OFF_K, 2 * tp, dkb * 8);
      short8 r1 = ldswz8(smem + OFF_K, 2 * tp + 1, dkb * 8);
#pragma unroll
      for (int e = 0; e < 8; ++e) {
        int dk = dkb * 8 + e;
        unsigned int pk = (unsigned int)(unsigned short)r0[e]
                        | ((unsigned int)(unsigned short)r1[e] << 16);
        int Lk = (dk << 7) + (tp << 2);
        *(unsigned int*)(smem + OFF_KT + (Lk ^ ((dk & 7) << 4))) = pk;
      }
    }
    if (wid == 0) {
      float gv = ((const float*)(smem + OFF_G))[lane];
#pragma unroll
      for (int off = 1; off < 64; off <<= 1) {
        float n = __shfl_up(gv, off);
        if (lane >= off) gv += n;
      }
      ((float*)(smem + OFF_CS))[lane] = gv;
      ((float*)(smem + OFF_EXC))[lane] = __expf(gv);
      float tot = __shfl(gv, 63);
      ((float*)(smem + OFF_ECT))[lane] = __expf(tot - gv);
    }
    __syncthreads();

    // ---- T2+T3: per-wave half MFMAs, then scale/scatter ----
    f32x4 aKK[2] = {}, aQK[2] = {}, aKS = {}, aQS = {};
    float oq[4];
#pragma unroll
    for (int kk = 0; kk < 4; ++kk) {
      int ke = kk * 32 + lq * 8;
      short8 avk = ldswz8(smem + OFF_K, 16 * rg + lr, ke);
      short8 avq = qcur[kk];
#pragma unroll
      for (int tc2 = 0; tc2 < 2; ++tc2) {
        short8 bvk = ldswz8(smem + OFF_K, 16 * (2 * half + tc2) + lr, ke);
        aKK[tc2] = __builtin_amdgcn_mfma_f32_16x16x32_bf16(avk, bvk, aKK[tc2], 0, 0, 0);
        aQK[tc2] = __builtin_amdgcn_mfma_f32_16x16x32_bf16(avq, bvk, aQK[tc2], 0, 0, 0);
      }
      short8 bH = ldswz8(smem + OFF_SH, 16 * half + lr, ke);
      short8 bL = ldswz8(smem + OFF_SL, 16 * half + lr, ke);
      aKS = __builtin_amdgcn_mfma_f32_16x16x32_bf16(avk, bH, aKS, 0, 0, 0);
      aKS = __builtin_amdgcn_mfma_f32_16x16x32_bf16(avk, bL, aKS, 0, 0, 0);
      aQS = __builtin_amdgcn_mfma_f32_16x16x32_bf16(avq, bH, aQS, 0, 0, 0);
      aQS = __builtin_amdgcn_mfma_f32_16x16x32_bf16(avq, bL, aQS, 0, 0, 0);
    }
    {
      const float* csp  = (const float*)(smem + OFF_CS);
      const float* excp = (const float*)(smem + OFF_EXC);
      const float* betp = (const float*)(smem + OFF_B2);
      const unsigned short* vp = (const unsigned short*)(smem + OFF_V);
      float cst[4], bt4[4], ext[4];
#pragma unroll
      for (int j = 0; j < 4; ++j) {
        int t = 16 * rg + lq * 4 + j;
        cst[j] = csp[t]; bt4[j] = betp[t]; ext[j] = excp[t];
      }
#pragma unroll
      for (int tc2 = 0; tc2 < 2; ++tc2) {
        int i = 16 * (2 * half + tc2) + lr;
        float csi = csp[i];
#pragma unroll
        for (int j = 0; j < 4; ++j) {
          int t = 16 * rg + lq * 4 + j;
          float e = __expf(cst[j] - csi);
          float av = (i < t) ? bt4[j] * e * aKK[tc2][j] : 0.f;
          ((float*)(smem + OFF_A2))[t * 68 + (i & 7) * 8 + (i >> 3)] = av;
          float mv = (i <= t) ? e * aQK[tc2][j] : 0.f;
          unsigned int mvb = f2bf(mv);
          unsigned int mvp = (unsigned int)dpp_mov<0xB1>((int)mvb);
          if (!(lr & 1)) {
            int Lm = (t << 7) + (i << 1);
            *(unsigned int*)(smem + OFF_MM + (Lm ^ ((t & 7) << 4))) = mvb | (mvp << 16);
          }
        }
      }
      int vcl = 16 * half + lr;
#pragma unroll
      for (int j = 0; j < 4; ++j) {
        int t = 16 * rg + lq * 4 + j;
        float vvv = bf2f(vp[t * 32 + vcl]);
        float x = bt4[j] * (vvv - ext[j] * aKS[j]);
        ((float*)(smem + OFF_X))[t * 33 + vcl] = x;
        oq[j] = ext[j] * aQS[j];
      }
    }
    __syncthreads();

    // ---- T4: waves0-3 substitution (X pre-hoisted to regs); waves4-7 stage next ----
    if (ct + 1 < TT / CC) loadQ(qnext, (ct + 1) * CC);
    if (wid < 4) {
      const float* A2p  = (const float*)(smem + OFF_A2);
      const float* Xp   = (const float*)(smem + OFF_X);
      const float* ectp = (const float*)(smem + OFF_ECT);
      const int col = tid >> 3, rr = tid & 7;
      float bbvX[8];
#pragma unroll
      for (int k = 0; k < 8; ++k) bbvX[k] = Xp[(8 * k + rr) * 33 + col];
      float bbv[8] = {0.f, 0.f, 0.f, 0.f, 0.f, 0.f, 0.f, 0.f};
#pragma unroll
      for (int t = 0; t < 64; ++t) {
        float4 a0 = *(const float4*)(A2p + t * 68 + rr * 8);
        float4 a1 = *(const float4*)(A2p + t * 68 + rr * 8 + 4);
        float sA = fmaf(a0.y, bbv[1], a0.x * bbv[0]);
        sA = fmaf(a0.z, bbv[2], sA); sA = fmaf(a0.w, bbv[3], sA);
        float sB = fmaf(a1.y, bbv[5], a1.x * bbv[4]);
        sB = fmaf(a1.z, bbv[6], sB); sB = fmaf(a1.w, bbv[7], sB);
        float s = row8_sum(sA + sB);
        float btv = bbvX[t >> 3] - s;
        if (rr == (t & 7)) bbv[t >> 3] = btv;
      }
#pragma unroll
      for (int k = 0; k < 8; ++k) {
        int t = 8 * k + rr;
        int Lb = (col << 7) + (t << 1);
        int Pb = Lb ^ ((col & 7) << 4);
        *(unsigned short*)(smem + OFF_BT + Pb)  = f2bf(bbv[k]);
        *(unsigned short*)(smem + OFF_BT2 + Pb) = f2bf(bbv[k] * ectp[t]);
      }
    } else if (ct + 1 < TT / CC) {
      stage_part((ct + 1) * CC);
    }
    __syncthreads();

    // ---- T5: O = oq + M@B; S = ecC*S + B2^T@K ----
    {
      f32x4 accO = (f32x4){oq[0], oq[1], oq[2], oq[3]};
#pragma unroll
      for (int kk2 = 0; kk2 < 2; ++kk2) {
        int ke = kk2 * 32 + lq * 8;
        short8 aM = ldswz7(smem + OFF_MM, 16 * rg + lr, ke);
        short8 bB = ldswz7(smem + OFF_BT, 16 * half + lr, ke);
        accO = __builtin_amdgcn_mfma_f32_16x16x32_bf16(aM, bB, accO, 0, 0, 0);
      }
      int vcl = 16 * half + lr;
#pragma unroll
      for (int j = 0; j < 4; ++j) {
        int t = 16 * rg + lq * 4 + j;
        long tg = (long)(bat * TT + ct * CC + t);
        ob[(tg * 32 + h) * 128 + vc * 32 + vcl] = f2bf(accO[j]);
      }

      f32x4 accP[2] = {};
#pragma unroll
      for (int kk2 = 0; kk2 < 2; ++kk2) {
        int ke = kk2 * 32 + lq * 8;
        short8 aB2 = ldswz7(smem + OFF_BT2, 16 * mr + lr, ke);
#pragma unroll
        for (int c4 = 0; c4 < 2; ++c4) {
          short8 bK = ldswz7(smem + OFF_KT, 16 * (2 * nc2 + c4) + lr, ke);
          accP[c4] = __builtin_amdgcn_mfma_f32_16x16x32_bf16(aB2, bK, accP[c4], 0, 0, 0);
        }
      }
      float ecC = ((const float*)(smem + OFF_EXC))[63];
#pragma unroll
      for (int c4 = 0; c4 < 2; ++c4)
#pragma unroll
        for (int j = 0; j < 4; ++j) {
          float sv = fmaf(ecC, Smast[c4][j], accP[c4][j]);
          Smast[c4][j] = sv;
          int vcr = 16 * mr + lq * 4 + j;
          int dk  = 16 * (2 * nc2 + c4) + lr;
          unsigned int hi = f2bf(sv);
          unsigned int lo = f2bf(sv - bf2f((unsigned short)hi));
          unsigned int hip = (unsigned int)dpp_mov<0xB1>((int)hi);
          unsigned int lop = (unsigned int)dpp_mov<0xB1>((int)lo);
          if (!(lr & 1)) {
            int Ls = (vcr << 8) + (dk << 1);
            int Ps = Ls ^ ((vcr & 7) << 4);
            *(unsigned int*)(smem + OFF_SH + Ps) = hi | (hip << 16);
            *(unsigned int*)(smem + OFF_SL + Ps) = lo | (lop << 16);
          }
        }
    }
    asm volatile("s_waitcnt vmcnt(0)" ::: "memory");
    __syncthreads();
  };

  short8 qA[4], qB[4];
  loadQ(qA, 0);
  stage_full(0);
  *(f32x4*)(smem + OFF_SH + tid * 32)      = (f32x4){0.f, 0.f, 0.f, 0.f};
  *(f32x4*)(smem + OFF_SH + tid * 32 + 16) = (f32x4){0.f, 0.f, 0.f, 0.f};
  asm volatile("s_waitcnt vmcnt(0)" ::: "memory");
  __syncthreads();

  for (int cp = 0; cp < TT / CC / 2; ++cp) {
    body(2 * cp, qA, qB);
    body(2 * cp + 1, qB, qA);
  }
}

// ---------------- gated RMSNorm * silu(z) -> bf16 ----------------
__global__ __launch_bounds__(256) void norm_silu(const unsigned short* __restrict__ ob,
                                                 const unsigned short* __restrict__ C1,
                                                 const float* __restrict__ nw,
                                                 unsigned short* __restrict__ nrm) {
  int unit = blockIdx.x * 4 + (threadIdx.x >> 6);
  int lane = threadIdx.x & 63;
  int m = unit >> 5, h = unit & 31;
  unsigned int uo = *(const unsigned int*)&ob[(long)unit * 128 + lane * 2];
  float o0 = bf2f((unsigned short)(uo & 0xffff));
  float o1 = bf2f((unsigned short)(uo >> 16));
  float ss = o0 * o0 + o1 * o1;
#pragma unroll
  for (int mm = 1; mm < 64; mm <<= 1) ss += __shfl_xor(ss, mm);
  float rs = rsqrtf(ss * (1.0f / 128.0f) + 1e-6f);
  unsigned int uz = *(const unsigned int*)&C1[(long)m * N1PAD + 8192 + h * 128 + lane * 2];
  float z0 = bf2f((unsigned short)(uz & 0xffff));
  float z1 = bf2f((unsigned short)(uz >> 16));
  float s0 = z0 / (1.f + expf(-z0));
  float s1 = z1 / (1.f + expf(-z1));
  float r0 = o0 * rs * nw[lane * 2] * s0;
  float r1 = o1 * rs * nw[lane * 2 + 1] * s1;
  unsigned int pk = (unsigned int)f2bf(r0) | ((unsigned int)f2bf(r1) << 16);
  *(unsigned int*)&nrm[(long)unit * 128 + lane * 2] = pk;
}

extern "C" void kernel_launch(void* const* d_in, const int* in_sizes, int n_in,
                              void* d_out, int out_size, void* d_ws, size_t ws_size,
                              hipStream_t stream) {
  const float* x    = (const float*)d_in[0];
  const float* Wqkv = (const float*)d_in[2];
  const float* Wz   = (const float*)d_in[3];
  const float* Wb   = (const float*)d_in[4];
  const float* Wa   = (const float*)d_in[5];
  const float* convw= (const float*)d_in[6];
  const float* dtb  = (const float*)d_in[7];
  const float* Alog = (const float*)d_in[8];
  const float* nw   = (const float*)d_in[9];
  const float* Wout = (const float*)d_in[10];
  float* out = (float*)d_out;

  char* ws = (char*)d_ws;
  const size_t OFF_C1    = 0;                    // bf16 [4096][12544]
  const size_t OFF_XB    = 102760448;            // bf16 [4096][2048]
  const size_t OFF_WCAT  = 119537664;            // bf16 [12544][2048]
  const size_t OFF_QB    = OFF_XB;               // over xb (post-GEMM1)
  const size_t OFF_KB    = 119537664;            // over wcat
  const size_t OFF_VB    = 136314880;            // over wcat
  const size_t OFF_EG    = 170917888;            // f32  [4096][32]  (raw g)
  const size_t OFF_BE    = 171442176;
  const size_t OFF_OB    = 171966464;            // bf16 [4096][32][128]
  const size_t OFF_NRM   = OFF_QB;               // over qb+kb (post-scan)
  const size_t OFF_WOUTB = OFF_VB;               // over vb (post-scan)

  unsigned short* C1    = (unsigned short*)(ws + OFF_C1);
  unsigned short* xb    = (unsigned short*)(ws + OFF_XB);
  unsigned short* wcat  = (unsigned short*)(ws + OFF_WCAT);
  unsigned short* qbuf  = (unsigned short*)(ws + OFF_QB);
  unsigned short* kbuf  = (unsigned short*)(ws + OFF_KB);
  unsigned short* vbuf  = (unsigned short*)(ws + OFF_VB);
  float*          egb   = (float*)(ws + OFF_EG);
  float*          betab = (float*)(ws + OFF_BE);
  unsigned short* obuf  = (unsigned short*)(ws + OFF_OB);
  unsigned short* nrm   = (unsigned short*)(ws + OFF_NRM);
  unsigned short* woutb = (unsigned short*)(ws + OFF_WOUTB);
  (void)ws_size; (void)in_sizes; (void)n_in; (void)out_size;

  static int smem_set = 0;
  if (!smem_set) {
    hipFuncSetAttribute(reinterpret_cast<const void*>(chunk_scan),
                        hipFuncAttributeMaxDynamicSharedMemorySize, SMEM_SZ);
    hipFuncSetAttribute(reinterpret_cast<const void*>(gemm256),
                        hipFuncAttributeMaxDynamicSharedMemorySize, 131072);
    hipFuncSetAttribute(reinterpret_cast<const void*>(gemm128x256),
                        hipFuncAttributeMaxDynamicSharedMemorySize, 98304);
    smem_set = 1;
  }

  cvt_bf16<<<8192, 256, 0, stream>>>(x, xb);
  build_wcat<<<25088, 256, 0, stream>>>(Wqkv, Wz, Wb, Wa, wcat);
  gemm256<<<dim3(N1PAD / 256, M_ROWS / 256), 512, 131072, stream>>>(xb, wcat, C1, N1PAD, 2048);
  conv_silu<<<512, 256, 0, stream>>>(C1, convw, qbuf, kbuf, vbuf);
  gbeta<<<512, 256, 0, stream>>>(C1, Alog, dtb, egb, betab);
  chunk_scan<<<256, 512, SMEM_SZ, stream>>>(qbuf, kbuf, vbuf, egb, betab, obuf);
  cvt_bf16<<<8192, 256, 0, stream>>>(Wout, woutb);
  norm_silu<<<32768, 256, 0, stream>>>(obuf, C1, nw, nrm);
  gemm128x256<<<dim3(2048 / 256, M_ROWS / 128), 512, 98304, stream>>>(nrm, woutb, out, 2048, 4096);
}

// Round 19
// 717.712 us; speedup vs baseline: 1.0309x; 1.0309x over previous
//
#include <hip/hip_runtime.h>

// dims
#define BB 2
#define TT 2048
#define HID 2048
#define HK 16
#define HV 32
#define DK 128
#define DV 128
#define KW 4
#define KEY_DIM 2048
#define VAL_DIM 4096
#define CONV_DIM 8192
#define N1PAD 12544     // 12352 padded to 256
#define M_ROWS 4096     // B*T
#define CC 64           // scan chunk length

typedef __attribute__((ext_vector_type(8))) short short8;
typedef __attribute__((ext_vector_type(8))) unsigned short ushort8;
typedef __attribute__((ext_vector_type(4))) float f32x4;

__device__ __forceinline__ unsigned short f2bf(float f) {
  union { float f; unsigned int u; } v; v.f = f;
  unsigned int r = v.u + 0x7FFFu + ((v.u >> 16) & 1u);
  return (unsigned short)(r >> 16);
}
__device__ __forceinline__ float bf2f(unsigned short u) {
  union { unsigned int u; float f; } v; v.u = ((unsigned int)u) << 16; return v.f;
}

// pure-VALU cross-lane ops via DPP
template <int CTRL>
__device__ __forceinline__ float dpp_add(float v) {
  union { float f; int i; } a, b;
  a.f = v;
  b.i = __builtin_amdgcn_update_dpp(0, a.i, CTRL, 0xf, 0xf, true);
  return a.f + b.f;
}
template <int CTRL>
__device__ __forceinline__ int dpp_mov(int v) {
  return __builtin_amdgcn_update_dpp(0, v, CTRL, 0xf, 0xf, true);
}
__device__ __forceinline__ float row16_sum(float v) {
  v = dpp_add<0xB1>(v); v = dpp_add<0x4E>(v);
  v = dpp_add<0x141>(v); v = dpp_add<0x140>(v);
  return v;
}
__device__ __forceinline__ float row8_sum(float v) {
  v = dpp_add<0xB1>(v); v = dpp_add<0x4E>(v); v = dpp_add<0x141>(v);
  return v;
}

__device__ __forceinline__ void gload_lds16(const unsigned short* g, unsigned short* l) {
  __builtin_amdgcn_global_load_lds((const __attribute__((address_space(1))) unsigned int*)g,
                                   (__attribute__((address_space(3))) unsigned int*)l,
                                   16, 0, 0);
}
__device__ __forceinline__ void gload_lds4(const float* g, unsigned short* l) {
  __builtin_amdgcn_global_load_lds((const __attribute__((address_space(1))) unsigned int*)g,
                                   (__attribute__((address_space(3))) unsigned int*)l,
                                   4, 0, 0);
}

// swizzled LDS bf16 reads: rows of 256B (sh=8) / 128B (sh=7); byte ^= ((row&7)<<4)
__device__ __forceinline__ short8 ldswz8(const char* base, int row, int e16) {
  int L = (row << 8) + (e16 << 1);
  return *(const short8*)(base + (L ^ ((row & 7) << 4)));
}
__device__ __forceinline__ short8 ldswz7(const char* base, int row, int e16) {
  int L = (row << 7) + (e16 << 1);
  return *(const short8*)(base + (L ^ ((row & 7) << 4)));
}

// ---------------- conversions ----------------
__global__ void cvt_bf16(const float* __restrict__ in, unsigned short* __restrict__ out) {
  long i = ((long)blockIdx.x * 256 + threadIdx.x) * 4;
  float4 v = *(const float4*)&in[i];
  unsigned long long p = (unsigned long long)f2bf(v.x)
                       | ((unsigned long long)f2bf(v.y) << 16)
                       | ((unsigned long long)f2bf(v.z) << 32)
                       | ((unsigned long long)f2bf(v.w) << 48);
  *(unsigned long long*)&out[i] = p;
}

__global__ void build_wcat(const float* __restrict__ wqkv, const float* __restrict__ wz,
                           const float* __restrict__ wb, const float* __restrict__ wa,
                           unsigned short* __restrict__ wcat) {
  long idx = (long)blockIdx.x * 256 + threadIdx.x;
  long e = idx * 4;
  long r = e >> 11;
  int cc = (int)(e & 2047);
  unsigned long long p = 0ULL;
  if (r < 12352) {
    const float* src;
    if (r < 8192)       src = wqkv + r * 2048;
    else if (r < 12288) src = wz + (r - 8192) * 2048;
    else if (r < 12320) src = wb + (r - 12288) * 2048;
    else                src = wa + (r - 12320) * 2048;
    float4 v = *(const float4*)&src[cc];
    p = (unsigned long long)f2bf(v.x)
      | ((unsigned long long)f2bf(v.y) << 16)
      | ((unsigned long long)f2bf(v.z) << 32)
      | ((unsigned long long)f2bf(v.w) << 48);
  }
  *(unsigned long long*)&wcat[e] = p;
}

// ---------------- pipelined GEMM staging helper (rows of 64 bf16 = 128B, swz7) ----------------
__device__ __forceinline__ void stage256(const unsigned short* __restrict__ G, long rb, int K,
                                         int kt, char* region, int r, int tid, int wid) {
  int i = r * 512 + tid;
  int row = i >> 3;
  int D = i << 4;
  int eb = (D ^ ((row & 7) << 4)) & 127;
  const unsigned short* src = G + (rb + row) * (long)K + kt * 64 + (eb >> 1);
  gload_lds16(src, (unsigned short*)region + r * 4096 + wid * 512);
}

// ---------------- GEMM 256x256 tile, BK=64, 8 waves, dbuf, swizzled (gemm1) ----------------
__global__ __launch_bounds__(512, 2) void gemm256(const unsigned short* __restrict__ A,
                                                  const unsigned short* __restrict__ Bw,
                                                  unsigned short* __restrict__ Cout,
                                                  int N, int K) {
  extern __shared__ char gs[];   // 131072
  const int tid = threadIdx.x, wid = tid >> 6, lane = tid & 63;
  const int lr = lane & 15, lq = lane >> 4;
  const long m0 = (long)blockIdx.y << 8;
  const long n0 = (long)blockIdx.x << 8;
  const int wr = wid >> 2, wc = wid & 3;
  const int nkt = K >> 6;

  f32x4 acc[8][4] = {};

#pragma unroll
  for (int r = 0; r < 4; ++r) {
    stage256(A, m0, K, 0, gs, r, tid, wid);
    stage256(Bw, n0, K, 0, gs + 32768, r, tid, wid);
  }
  asm volatile("s_waitcnt vmcnt(0)" ::: "memory");
  __syncthreads();

  for (int kt = 0; kt < nkt; ++kt) {
    char* cur = gs + ((kt & 1) << 16);
    char* nxt = gs + (((kt + 1) & 1) << 16);
    const char* cA = cur;
    const char* cB = cur + 32768;
    const bool pf = (kt + 1 < nkt);
    short8 bf[2][4];
#pragma unroll
    for (int p = 0; p < 4; ++p) {
      if (pf) {
        stage256(A, m0, K, kt + 1, nxt, p, tid, wid);
        stage256(Bw, n0, K, kt + 1, nxt + 32768, p, tid, wid);
      }
      if (p == 0) {
#pragma unroll
        for (int ks = 0; ks < 2; ++ks)
#pragma unroll
          for (int cf = 0; cf < 4; ++cf)
            bf[ks][cf] = ldswz7(cB, wc * 64 + cf * 16 + lr, ks * 32 + lq * 8);
      }
      short8 af[2][2];
#pragma unroll
      for (int ks = 0; ks < 2; ++ks)
#pragma unroll
        for (int rr = 0; rr < 2; ++rr)
          af[ks][rr] = ldswz7(cA, wr * 128 + (p * 2 + rr) * 16 + lr, ks * 32 + lq * 8);
      __builtin_amdgcn_s_setprio(1);
#pragma unroll
      for (int ks = 0; ks < 2; ++ks)
#pragma unroll
        for (int rr = 0; rr < 2; ++rr)
#pragma unroll
          for (int cf = 0; cf < 4; ++cf)
            acc[p * 2 + rr][cf] = __builtin_amdgcn_mfma_f32_16x16x32_bf16(
                af[ks][rr], bf[ks][cf], acc[p * 2 + rr][cf], 0, 0, 0);
      __builtin_amdgcn_s_setprio(0);
    }
    asm volatile("s_waitcnt vmcnt(0)" ::: "memory");
    __syncthreads();
  }

  const long rbase = m0 + wr * 128 + lq * 4;
  const long cbase = n0 + wc * 64 + lr;
#pragma unroll
  for (int rf = 0; rf < 8; ++rf)
#pragma unroll
    for (int cf = 0; cf < 4; ++cf)
#pragma unroll
      for (int j = 0; j < 4; ++j)
        Cout[(rbase + rf * 16 + j) * N + cbase + cf * 16] = f2bf(acc[rf][cf][j]);
}

// ---------------- GEMM 128x256 tile, BK=64, 8 waves, dbuf, swizzled, f32 out (gemm2) ----------------
__global__ __launch_bounds__(512, 2) void gemm128x256(const unsigned short* __restrict__ A,
                                                      const unsigned short* __restrict__ Bw,
                                                      float* __restrict__ Cout,
                                                      int N, int K) {
  extern __shared__ char gs[];   // 2 x (A 16KB + B 32KB) = 98304
  const int tid = threadIdx.x, wid = tid >> 6, lane = tid & 63;
  const int lr = lane & 15, lq = lane >> 4;
  const long m0 = (long)blockIdx.y << 7;
  const long n0 = (long)blockIdx.x << 8;
  const int wr = wid >> 2, wc = wid & 3;   // wave tile 64x64
  const int nkt = K >> 6;

  f32x4 acc[4][4] = {};

#pragma unroll
  for (int r = 0; r < 2; ++r) stage256(A, m0, K, 0, gs, r, tid, wid);
#pragma unroll
  for (int r = 0; r < 4; ++r) stage256(Bw, n0, K, 0, gs + 16384, r, tid, wid);
  asm volatile("s_waitcnt vmcnt(0)" ::: "memory");
  __syncthreads();

  for (int kt = 0; kt < nkt; ++kt) {
    char* cur = gs + (kt & 1) * 49152;
    char* nxt = gs + ((kt + 1) & 1) * 49152;
    const char* cA = cur;
    const char* cB = cur + 16384;
    const bool pf = (kt + 1 < nkt);
    short8 bf[2][4];
#pragma unroll
    for (int p = 0; p < 4; ++p) {
      if (pf) {
        if (p < 2) stage256(A, m0, K, kt + 1, nxt, p, tid, wid);
        stage256(Bw, n0, K, kt + 1, nxt + 16384, p, tid, wid);
      }
      if (p == 0) {
#pragma unroll
        for (int ks = 0; ks < 2; ++ks)
#pragma unroll
          for (int cf = 0; cf < 4; ++cf)
            bf[ks][cf] = ldswz7(cB, wc * 64 + cf * 16 + lr, ks * 32 + lq * 8);
      }
      short8 af[2];
#pragma unroll
      for (int ks = 0; ks < 2; ++ks)
        af[ks] = ldswz7(cA, wr * 64 + p * 16 + lr, ks * 32 + lq * 8);
      __builtin_amdgcn_s_setprio(1);
#pragma unroll
      for (int ks = 0; ks < 2; ++ks)
#pragma unroll
        for (int cf = 0; cf < 4; ++cf)
          acc[p][cf] = __builtin_amdgcn_mfma_f32_16x16x32_bf16(
              af[ks], bf[ks][cf], acc[p][cf], 0, 0, 0);
      __builtin_amdgcn_s_setprio(0);
    }
    asm volatile("s_waitcnt vmcnt(0)" ::: "memory");
    __syncthreads();
  }

  const long rbase = m0 + wr * 64 + lq * 4;
  const long cbase = n0 + wc * 64 + lr;
#pragma unroll
  for (int rf = 0; rf < 4; ++rf)
#pragma unroll
    for (int cf = 0; cf < 4; ++cf)
#pragma unroll
      for (int j = 0; j < 4; ++j)
        Cout[(rbase + rf * 16 + j) * N + cbase + cf * 16] = acc[rf][cf][j];
}

// ---------------- depthwise causal conv1d + silu (+ fused l2norm for q,k) ----------------
__global__ __launch_bounds__(256) void conv_silu(const unsigned short* __restrict__ C1,
                                                 const float* __restrict__ convw,
                                                 unsigned short* __restrict__ qb,
                                                 unsigned short* __restrict__ kb,
                                                 unsigned short* __restrict__ vb) {
  const int bid = blockIdx.x;             // 512 = cb(4) * tblk(64) * b(2)
  const int cb = bid & 3, tblk = (bid >> 2) & 63, b = bid >> 8;
  const int c0 = cb * 2048 + threadIdx.x * 8;
  float w0[8], w1[8], w2[8], w3[8];
#pragma unroll
  for (int j = 0; j < 8; ++j) {
    float4 wv = *(const float4*)&convw[(c0 + j) * 4];
    w0[j] = wv.x; w1[j] = wv.y; w2[j] = wv.z; w3[j] = wv.w;
  }
  const int t0 = tblk * 32;
  const long rowbase = ((long)b * TT) * N1PAD + c0;
  float x0[8], x1[8], x2[8];
#pragma unroll
  for (int j = 0; j < 8; ++j) { x0[j] = 0.f; x1[j] = 0.f; x2[j] = 0.f; }
  if (t0 >= 1) { ushort8 r = *(const ushort8*)&C1[rowbase + (long)(t0 - 1) * N1PAD];
#pragma unroll
    for (int j = 0; j < 8; ++j) x2[j] = bf2f(r[j]); }
  if (t0 >= 2) { ushort8 r = *(const ushort8*)&C1[rowbase + (long)(t0 - 2) * N1PAD];
#pragma unroll
    for (int j = 0; j < 8; ++j) x1[j] = bf2f(r[j]); }
  if (t0 >= 3) { ushort8 r = *(const ushort8*)&C1[rowbase + (long)(t0 - 3) * N1PAD];
#pragma unroll
    for (int j = 0; j < 8; ++j) x0[j] = bf2f(r[j]); }

  const float nsc = (cb == 0) ? 0.08838834764831845f : 1.0f;
  for (int t = t0; t < t0 + 32; ++t) {
    ushort8 rr = *(const ushort8*)&C1[rowbase + (long)t * N1PAD];
    float ys[8];
#pragma unroll
    for (int j = 0; j < 8; ++j) {
      float x3 = bf2f(rr[j]);
      float y = w0[j] * x0[j] + w1[j] * x1[j] + w2[j] * x2[j] + w3[j] * x3;
      ys[j] = y / (1.f + __expf(-y));
      x0[j] = x1[j]; x1[j] = x2[j]; x2[j] = x3;
    }
    if (cb < 2) {
      float ss = 0.f;
#pragma unroll
      for (int j = 0; j < 8; ++j) ss = fmaf(ys[j], ys[j], ss);
      ss = row16_sum(ss);
      float sc = nsc / fmaxf(sqrtf(ss), 1e-12f);
#pragma unroll
      for (int j = 0; j < 8; ++j) ys[j] *= sc;
    }
    ushort8 outp;
#pragma unroll
    for (int j = 0; j < 8; ++j) outp[j] = f2bf(ys[j]);
    long m = (long)b * TT + t;
    if (cb == 0)      *(ushort8*)&qb[m * 2048 + threadIdx.x * 8] = outp;
    else if (cb == 1) *(ushort8*)&kb[m * 2048 + threadIdx.x * 8] = outp;
    else              *(ushort8*)&vb[m * 4096 + (cb - 2) * 2048 + threadIdx.x * 8] = outp;
  }
}

// ---------------- raw g (log decay) and beta ----------------
__global__ void gbeta(const unsigned short* __restrict__ C1, const float* __restrict__ Alog,
                      const float* __restrict__ dtb, float* __restrict__ graw, float* __restrict__ betab) {
  int idx = blockIdx.x * 256 + threadIdx.x;
  int m = idx >> 5, h = idx & 31;
  float a = bf2f(C1[(long)m * N1PAD + 12320 + h]);
  float bl = bf2f(C1[(long)m * N1PAD + 12288 + h]);
  float xsp = a + dtb[h];
  float sp = (xsp > 20.f) ? xsp : log1pf(expf(xsp));
  graw[idx] = -expf(Alog[h]) * sp;
  betab[idx] = 1.f / (1.f + expf(-bl));
}

// ---------------- chunked gated delta rule scan (MFMA WY-form, 512 thr coop, 97KB LDS) ----------------
// LDS map (bytes):
#define OFF_K   0          // [64][128] bf16 swz8 — 16384 (single buffer)
#define OFF_V   16384      // [64][32] bf16 linear — 4096
#define OFF_G   20480      // [64] f32
#define OFF_B2  20736      // [64] f32
#define OFF_KT  20992      // [128 dk][64 t] bf16, swz keyed dk&7 — 16384
#define OFF_SH  37376      // St hi [32][128] bf16 swz8 — 8192
#define OFF_SL  45568      // St lo — 8192
#define OFF_A2  53760      // [64][68] f32 padded — 17408
#define OFF_MM  71168      // M [64][64] bf16 swz7 — 8192
#define OFF_BT  79360      // Bt [32][64] bf16 swz7 — 4096
#define OFF_BT2 83456      // 4096
#define OFF_X   87552      // [64][33] f32 padded — 8448
#define OFF_CS  96000
#define OFF_EXC 96256
#define OFF_ECT 96512
#define SMEM_SZ 96768

__global__ __launch_bounds__(512, 2) void chunk_scan(const unsigned short* __restrict__ qb,
                                                     const unsigned short* __restrict__ kb,
                                                     const unsigned short* __restrict__ vb,
                                                     const float* __restrict__ graw,
                                                     const float* __restrict__ betab,
                                                     unsigned short* __restrict__ ob) {
  extern __shared__ char smem[];
  const int w = blockIdx.x;
  const int rdec = w >> 5, gdec = w & 31;
  const int bat = gdec >> 4, hk = gdec & 15;
  const int h = hk * 2 + (rdec >> 2), vc = rdec & 3;
  const int tid = threadIdx.x, wid = tid >> 6, lane = tid & 63;
  const int lr = lane & 15, lq = lane >> 4;
  const int rg = wid & 3, half = wid >> 2;
  const int mr = wid & 1, nc2 = (wid >> 1) & 3;

  const long kqoff = ((long)bat * TT) * 2048 + hk * 128;
  const long voff  = ((long)bat * TT) * 4096 + h * 128 + vc * 32;
  const long goff  = ((long)bat * TT) * 32 + h;

  f32x4 Smast[2] = {};

  auto stage_full = [&](int t0c) {
#pragma unroll
    for (int it = 0; it < 2; ++it) {
      int i = it * 512 + tid;
      int row = i >> 4;
      int L = ((i & 15) << 4) ^ ((row & 7) << 4);
      long grow = (long)(t0c + row) * 2048 + (L >> 1);
      gload_lds16(kb + kqoff + grow, (unsigned short*)(smem + OFF_K) + it * 4096 + wid * 512);
    }
    if (tid < 256)
      gload_lds16(vb + voff + (long)(t0c + (tid >> 2)) * 4096 + (tid & 3) * 8,
                  (unsigned short*)(smem + OFF_V) + wid * 512);
    if (wid == 6) gload_lds4(graw  + goff + (long)(t0c + lane) * 32, (unsigned short*)(smem + OFF_G));
    if (wid == 7) gload_lds4(betab + goff + (long)(t0c + lane) * 32, (unsigned short*)(smem + OFF_B2));
  };
  auto stage_part = [&](int t0c) {   // waves 4-7
    int tid2 = tid - 256, wid2 = wid - 4;
#pragma unroll
    for (int it = 0; it < 4; ++it) {
      int i = it * 256 + tid2;
      int row = i >> 4;
      int L = ((i & 15) << 4) ^ ((row & 7) << 4);
      long grow = (long)(t0c + row) * 2048 + (L >> 1);
      gload_lds16(kb + kqoff + grow, (unsigned short*)(smem + OFF_K) + it * 2048 + wid2 * 512);
    }
    gload_lds16(vb + voff + (long)(t0c + (tid2 >> 2)) * 4096 + (tid2 & 3) * 8,
                (unsigned short*)(smem + OFF_V) + wid2 * 512);
    if (wid == 4) gload_lds4(graw  + goff + (long)(t0c + lane) * 32, (unsigned short*)(smem + OFF_G));
    if (wid == 5) gload_lds4(betab + goff + (long)(t0c + lane) * 32, (unsigned short*)(smem + OFF_B2));
  };
  auto loadQ = [&](short8 (&qr)[4], int t0c) {
#pragma unroll
    for (int kk = 0; kk < 4; ++kk)
      qr[kk] = *(const short8*)&qb[kqoff + (long)(t0c + 16 * rg + lr) * 2048 + kk * 32 + lq * 8];
  };

  auto body = [&](int ct, short8 (&qcur)[4], short8 (&qnext)[4]) {
    // ---- T1: kT transpose (all 512); wave0 cumsum+exp tables ----
    {
      int tp = tid & 31, dkb = tid >> 5;
      short8 r0 = ldswz8(smem + OFF_K, 2 * tp, dkb * 8);
      short8 r1 = ldswz8(smem + OFF_K, 2 * tp + 1, dkb * 8);
#pragma unroll
      for (int e = 0; e < 8; ++e) {
        int dk = dkb * 8 + e;
        unsigned int pk = (unsigned int)(unsigned short)r0[e]
                        | ((unsigned int)(unsigned short)r1[e] << 16);
        int Lk = (dk << 7) + (tp << 2);
        *(unsigned int*)(smem + OFF_KT + (Lk ^ ((dk & 7) << 4))) = pk;
      }
    }
    if (wid == 0) {
      float gv = ((const float*)(smem + OFF_G))[lane];
#pragma unroll
      for (int off = 1; off < 64; off <<= 1) {
        float n = __shfl_up(gv, off);
        if (lane >= off) gv += n;
      }
      ((float*)(smem + OFF_CS))[lane] = gv;
      ((float*)(smem + OFF_EXC))[lane] = __expf(gv);
      float tot = __shfl(gv, 63);
      ((float*)(smem + OFF_ECT))[lane] = __expf(tot - gv);
    }
    __syncthreads();

    // ---- T2+T3: per-wave half MFMAs, then scale/scatter ----
    f32x4 aKK[2] = {}, aQK[2] = {}, aKS = {}, aQS = {};
    float oq[4];
#pragma unroll
    for (int kk = 0; kk < 4; ++kk) {
      int ke = kk * 32 + lq * 8;
      short8 avk = ldswz8(smem + OFF_K, 16 * rg + lr, ke);
      short8 avq = qcur[kk];
#pragma unroll
      for (int tc2 = 0; tc2 < 2; ++tc2) {
        short8 bvk = ldswz8(smem + OFF_K, 16 * (2 * half + tc2) + lr, ke);
        aKK[tc2] = __builtin_amdgcn_mfma_f32_16x16x32_bf16(avk, bvk, aKK[tc2], 0, 0, 0);
        aQK[tc2] = __builtin_amdgcn_mfma_f32_16x16x32_bf16(avq, bvk, aQK[tc2], 0, 0, 0);
      }
      short8 bH = ldswz8(smem + OFF_SH, 16 * half + lr, ke);
      short8 bL = ldswz8(smem + OFF_SL, 16 * half + lr, ke);
      aKS = __builtin_amdgcn_mfma_f32_16x16x32_bf16(avk, bH, aKS, 0, 0, 0);
      aKS = __builtin_amdgcn_mfma_f32_16x16x32_bf16(avk, bL, aKS, 0, 0, 0);
      aQS = __builtin_amdgcn_mfma_f32_16x16x32_bf16(avq, bH, aQS, 0, 0, 0);
      aQS = __builtin_amdgcn_mfma_f32_16x16x32_bf16(avq, bL, aQS, 0, 0, 0);
    }
    {
      const float* csp  = (const float*)(smem + OFF_CS);
      const float* excp = (const float*)(smem + OFF_EXC);
      const float* betp = (const float*)(smem + OFF_B2);
      const unsigned short* vp = (const unsigned short*)(smem + OFF_V);
      float cst[4], bt4[4], ext[4];
#pragma unroll
      for (int j = 0; j < 4; ++j) {
        int t = 16 * rg + lq * 4 + j;
        cst[j] = csp[t]; bt4[j] = betp[t]; ext[j] = excp[t];
      }
#pragma unroll
      for (int tc2 = 0; tc2 < 2; ++tc2) {
        int i = 16 * (2 * half + tc2) + lr;
        float csi = csp[i];
#pragma unroll
        for (int j = 0; j < 4; ++j) {
          int t = 16 * rg + lq * 4 + j;
          float e = __expf(cst[j] - csi);
          float av = (i < t) ? bt4[j] * e * aKK[tc2][j] : 0.f;
          ((float*)(smem + OFF_A2))[t * 68 + (i & 7) * 8 + (i >> 3)] = av;
          float mv = (i <= t) ? e * aQK[tc2][j] : 0.f;
          unsigned int mvb = f2bf(mv);
          unsigned int mvp = (unsigned int)dpp_mov<0xB1>((int)mvb);
          if (!(lr & 1)) {
            int Lm = (t << 7) + (i << 1);
            *(unsigned int*)(smem + OFF_MM + (Lm ^ ((t & 7) << 4))) = mvb | (mvp << 16);
          }
        }
      }
      int vcl = 16 * half + lr;
#pragma unroll
      for (int j = 0; j < 4; ++j) {
        int t = 16 * rg + lq * 4 + j;
        float vvv = bf2f(vp[t * 32 + vcl]);
        float x = bt4[j] * (vvv - ext[j] * aKS[j]);
        ((float*)(smem + OFF_X))[t * 33 + vcl] = x;
        oq[j] = ext[j] * aQS[j];
      }
    }
    __syncthreads();

    // ---- T4: waves0-3 substitution (X pre-hoisted to regs); waves4-7 stage next ----
    if (ct + 1 < TT / CC) loadQ(qnext, (ct + 1) * CC);
    if (wid < 4) {
      const float* A2p  = (const float*)(smem + OFF_A2);
      const float* Xp   = (const float*)(smem + OFF_X);
      const float* ectp = (const float*)(smem + OFF_ECT);
      const int col = tid >> 3, rr = tid & 7;
      float bbvX[8];
#pragma unroll
      for (int k = 0; k < 8; ++k) bbvX[k] = Xp[(8 * k + rr) * 33 + col];
      float bbv[8] = {0.f, 0.f, 0.f, 0.f, 0.f, 0.f, 0.f, 0.f};
#pragma unroll
      for (int t = 0; t < 64; ++t) {
        float4 a0 = *(const float4*)(A2p + t * 68 + rr * 8);
        float4 a1 = *(const float4*)(A2p + t * 68 + rr * 8 + 4);
        float sA = fmaf(a0.y, bbv[1], a0.x * bbv[0]);
        sA = fmaf(a0.z, bbv[2], sA); sA = fmaf(a0.w, bbv[3], sA);
        float sB = fmaf(a1.y, bbv[5], a1.x * bbv[4]);
        sB = fmaf(a1.z, bbv[6], sB); sB = fmaf(a1.w, bbv[7], sB);
        float s = row8_sum(sA + sB);
        float btv = bbvX[t >> 3] - s;
        if (rr == (t & 7)) bbv[t >> 3] = btv;
      }
#pragma unroll
      for (int k = 0; k < 8; ++k) {
        int t = 8 * k + rr;
        int Lb = (col << 7) + (t << 1);
        int Pb = Lb ^ ((col & 7) << 4);
        *(unsigned short*)(smem + OFF_BT + Pb)  = f2bf(bbv[k]);
        *(unsigned short*)(smem + OFF_BT2 + Pb) = f2bf(bbv[k] * ectp[t]);
      }
    } else if (ct + 1 < TT / CC) {
      stage_part((ct + 1) * CC);
    }
    __syncthreads();

    // ---- T5: O = oq + M@B; S = ecC*S + B2^T@K ----
    {
      f32x4 accO = (f32x4){oq[0], oq[1], oq[2], oq[3]};
#pragma unroll
      for (int kk2 = 0; kk2 < 2; ++kk2) {
        int ke = kk2 * 32 + lq * 8;
        short8 aM = ldswz7(smem + OFF_MM, 16 * rg + lr, ke);
        short8 bB = ldswz7(smem + OFF_BT, 16 * half + lr, ke);
        accO = __builtin_amdgcn_mfma_f32_16x16x32_bf16(aM, bB, accO, 0, 0, 0);
      }
      int vcl = 16 * half + lr;
#pragma unroll
      for (int j = 0; j < 4; ++j) {
        int t = 16 * rg + lq * 4 + j;
        long tg = (long)(bat * TT + ct * CC + t);
        ob[(tg * 32 + h) * 128 + vc * 32 + vcl] = f2bf(accO[j]);
      }

      f32x4 accP[2] = {};
#pragma unroll
      for (int kk2 = 0; kk2 < 2; ++kk2) {
        int ke = kk2 * 32 + lq * 8;
        short8 aB2 = ldswz7(smem + OFF_BT2, 16 * mr + lr, ke);
#pragma unroll
        for (int c4 = 0; c4 < 2; ++c4) {
          short8 bK = ldswz7(smem + OFF_KT, 16 * (2 * nc2 + c4) + lr, ke);
          accP[c4] = __builtin_amdgcn_mfma_f32_16x16x32_bf16(aB2, bK, accP[c4], 0, 0, 0);
        }
      }
      float ecC = ((const float*)(smem + OFF_EXC))[63];
#pragma unroll
      for (int c4 = 0; c4 < 2; ++c4)
#pragma unroll
        for (int j = 0; j < 4; ++j) {
          float sv = fmaf(ecC, Smast[c4][j], accP[c4][j]);
          Smast[c4][j] = sv;
          int vcr = 16 * mr + lq * 4 + j;
          int dk  = 16 * (2 * nc2 + c4) + lr;
          unsigned int hi = f2bf(sv);
          unsigned int lo = f2bf(sv - bf2f((unsigned short)hi));
          unsigned int hip = (unsigned int)dpp_mov<0xB1>((int)hi);
          unsigned int lop = (unsigned int)dpp_mov<0xB1>((int)lo);
          if (!(lr & 1)) {
            int Ls = (vcr << 8) + (dk << 1);
            int Ps = Ls ^ ((vcr & 7) << 4);
            *(unsigned int*)(smem + OFF_SH + Ps) = hi | (hip << 16);
            *(unsigned int*)(smem + OFF_SL + Ps) = lo | (lop << 16);
          }
        }
    }
    asm volatile("s_waitcnt vmcnt(0)" ::: "memory");
    __syncthreads();
  };

  short8 qA[4], qB[4];
  loadQ(qA, 0);
  stage_full(0);
  *(f32x4*)(smem + OFF_SH + tid * 32)      = (f32x4){0.f, 0.f, 0.f, 0.f};
  *(f32x4*)(smem + OFF_SH + tid * 32 + 16) = (f32x4){0.f, 0.f, 0.f, 0.f};
  asm volatile("s_waitcnt vmcnt(0)" ::: "memory");
  __syncthreads();

  for (int cp = 0; cp < TT / CC / 2; ++cp) {
    body(2 * cp, qA, qB);
    body(2 * cp + 1, qB, qA);
  }
}

// ---------------- gated RMSNorm * silu(z) -> bf16 ----------------
__global__ __launch_bounds__(256) void norm_silu(const unsigned short* __restrict__ ob,
                                                 const unsigned short* __restrict__ C1,
                                                 const float* __restrict__ nw,
                                                 unsigned short* __restrict__ nrm) {
  int unit = blockIdx.x * 4 + (threadIdx.x >> 6);
  int lane = threadIdx.x & 63;
  int m = unit >> 5, h = unit & 31;
  unsigned int uo = *(const unsigned int*)&ob[(long)unit * 128 + lane * 2];
  float o0 = bf2f((unsigned short)(uo & 0xffff));
  float o1 = bf2f((unsigned short)(uo >> 16));
  float ss = o0 * o0 + o1 * o1;
#pragma unroll
  for (int mm = 1; mm < 64; mm <<= 1) ss += __shfl_xor(ss, mm);
  float rs = rsqrtf(ss * (1.0f / 128.0f) + 1e-6f);
  unsigned int uz = *(const unsigned int*)&C1[(long)m * N1PAD + 8192 + h * 128 + lane * 2];
  float z0 = bf2f((unsigned short)(uz & 0xffff));
  float z1 = bf2f((unsigned short)(uz >> 16));
  float s0 = z0 / (1.f + expf(-z0));
  float s1 = z1 / (1.f + expf(-z1));
  float r0 = o0 * rs * nw[lane * 2] * s0;
  float r1 = o1 * rs * nw[lane * 2 + 1] * s1;
  unsigned int pk = (unsigned int)f2bf(r0) | ((unsigned int)f2bf(r1) << 16);
  *(unsigned int*)&nrm[(long)unit * 128 + lane * 2] = pk;
}

extern "C" void kernel_launch(void* const* d_in, const int* in_sizes, int n_in,
                              void* d_out, int out_size, void* d_ws, size_t ws_size,
                              hipStream_t stream) {
  const float* x    = (const float*)d_in[0];
  const float* Wqkv = (const float*)d_in[2];
  const float* Wz   = (const float*)d_in[3];
  const float* Wb   = (const float*)d_in[4];
  const float* Wa   = (const float*)d_in[5];
  const float* convw= (const float*)d_in[6];
  const float* dtb  = (const float*)d_in[7];
  const float* Alog = (const float*)d_in[8];
  const float* nw   = (const float*)d_in[9];
  const float* Wout = (const float*)d_in[10];
  float* out = (float*)d_out;

  char* ws = (char*)d_ws;
  const size_t OFF_C1    = 0;                    // bf16 [4096][12544]
  const size_t OFF_XB    = 102760448;            // bf16 [4096][2048]
  const size_t OFF_WCAT  = 119537664;            // bf16 [12544][2048]
  const size_t OFF_QB    = OFF_XB;               // over xb (post-GEMM1)
  const size_t OFF_KB    = 119537664;            // over wcat
  const size_t OFF_VB    = 136314880;            // over wcat
  const size_t OFF_EG    = 170917888;            // f32  [4096][32]  (raw g)
  const size_t OFF_BE    = 171442176;
  const size_t OFF_OB    = 171966464;            // bf16 [4096][32][128]
  const size_t OFF_NRM   = OFF_QB;               // over qb+kb (post-scan)
  const size_t OFF_WOUTB = OFF_VB;               // over vb (post-scan)

  unsigned short* C1    = (unsigned short*)(ws + OFF_C1);
  unsigned short* xb    = (unsigned short*)(ws + OFF_XB);
  unsigned short* wcat  = (unsigned short*)(ws + OFF_WCAT);
  unsigned short* qbuf  = (unsigned short*)(ws + OFF_QB);
  unsigned short* kbuf  = (unsigned short*)(ws + OFF_KB);
  unsigned short* vbuf  = (unsigned short*)(ws + OFF_VB);
  float*          egb   = (float*)(ws + OFF_EG);
  float*          betab = (float*)(ws + OFF_BE);
  unsigned short* obuf  = (unsigned short*)(ws + OFF_OB);
  unsigned short* nrm   = (unsigned short*)(ws + OFF_NRM);
  unsigned short* woutb = (unsigned short*)(ws + OFF_WOUTB);
  (void)ws_size; (void)in_sizes; (void)n_in; (void)out_size;

  static int smem_set = 0;
  if (!smem_set) {
    hipFuncSetAttribute(reinterpret_cast<const void*>(chunk_scan),
                        hipFuncAttributeMaxDynamicSharedMemorySize, SMEM_SZ);
    hipFuncSetAttribute(reinterpret_cast<const void*>(gemm256),
                        hipFuncAttributeMaxDynamicSharedMemorySize, 131072);
    hipFuncSetAttribute(reinterpret_cast<const void*>(gemm128x256),
                        hipFuncAttributeMaxDynamicSharedMemorySize, 98304);
    smem_set = 1;
  }

  cvt_bf16<<<8192, 256, 0, stream>>>(x, xb);
  build_wcat<<<25088, 256, 0, stream>>>(Wqkv, Wz, Wb, Wa, wcat);
  gemm256<<<dim3(N1PAD / 256, M_ROWS / 256), 512, 131072, stream>>>(xb, wcat, C1, N1PAD, 2048);
  conv_silu<<<512, 256, 0, stream>>>(C1, convw, qbuf, kbuf, vbuf);
  gbeta<<<512, 256, 0, stream>>>(C1, Alog, dtb, egb, betab);
  chunk_scan<<<256, 512, SMEM_SZ, stream>>>(qbuf, kbuf, vbuf, egb, betab, obuf);
  cvt_bf16<<<8192, 256, 0, stream>>>(Wout, woutb);
  norm_silu<<<32768, 256, 0, stream>>>(obuf, C1, nw, nrm);
  gemm128x256<<<dim3(2048 / 256, M_ROWS / 128), 512, 98304, stream>>>(nrm, woutb, out, 2048, 4096);
}